// Round 6
// baseline (267.275 us; speedup 1.0000x reference)
//
#include <hip/hip_runtime.h>

// ---------------------------------------------------------------------------
// QuantizedShaper: B=256, L=8192, DIM=256, NPAT=64, HIST=32, WIN=8, T=1024.
//
//   scores r_t[p] = clip( sum_h xpad[t*8+h] * W2[p,h] + bias2[p], 0, 6 )
//   out[b, t*8+w] = relu( shapes_w[w, idx[t,b]] - x[b, t*8+w] )
//
// R6 scan: 4 patterns/lane (p = 4*(lane&15)+k), rows replicated (lanes
// l,l+16,l+32,l+48 read the same LDS word -> broadcast). Global argmax =
// 2-level local max tree + 4 within-row DPP stages; gmax lands in EVERY
// lane (no readlane / ballot on the chain). av/v updates via e_k=(v_k==gmax)
// cndmask; winner index extracted off-chain (4 ballots + min) for idxb only.
// fp op order identical to reference: av' = (av + prob) - 1/64.
// ---------------------------------------------------------------------------

constexpr int Bb = 256, Ll = 8192, DIMc = 256, NPAT = 64, HIST = 32, WINc = 8;
constexpr int Tt = Ll / WINc;   // 1024
constexpr int TC = 32;          // t-chunk
constexpr int NC = Tt / TC;     // 32 chunks
constexpr float CINV = 1.0f / 64.0f;

#define DPP_MAXF(m, ctrl)                                                      \
  do {                                                                         \
    int _mi = __float_as_int(m);                                               \
    int _ti = __builtin_amdgcn_update_dpp(_mi, _mi, (ctrl), 0xF, 0xF, false);  \
    (m) = fmaxf((m), __int_as_float(_ti));                                     \
  } while (0)

// one block per pattern p: W2[p,0..31] + bias2[p]
__global__ __launch_bounds__(256) void precompute_kernel(
    const float* __restrict__ conv_w, const float* __restrict__ conv_b,
    const float* __restrict__ keys_w, float* __restrict__ wsf) {
  __shared__ float part[8][32];
  __shared__ float bred[4];
  const int p = blockIdx.x;
  const int t = threadIdx.x;
  const int h = t & 31, g = t >> 5;
  const float* kwp = keys_w + (size_t)p * DIMc;

  float acc = 0.f;
#pragma unroll
  for (int dd = 0; dd < 32; ++dd) {
    int d = g * 32 + dd;
    acc = fmaf(kwp[d], conv_w[d * HIST + h], acc);
  }
  part[g][h] = acc;

  float bp = kwp[t] * conv_b[t];
#pragma unroll
  for (int off = 32; off; off >>= 1) bp += __shfl_down(bp, off);
  if ((t & 63) == 0) bred[t >> 6] = bp;
  __syncthreads();

  if (t < 32) {
    float s = 0.f;
#pragma unroll
    for (int gg = 0; gg < 8; ++gg) s += part[gg][t];
    wsf[(t >> 2) * (NPAT * 4) + p * 4 + (t & 3)] = s;  // float4-friendly
  } else if (t == 32) {
    wsf[NPAT * HIST + p] = (bred[0] + bred[1]) + (bred[2] + bred[3]);
  }
}

__global__ __launch_bounds__(256) void shaper_kernel(
    const float* __restrict__ x, const float* __restrict__ avg_init,
    const float* __restrict__ shapes_w, const float* __restrict__ wsf,
    float* __restrict__ out) {
  __shared__ __align__(16) float xpad[HIST - 1 + Ll + 1];
  __shared__ __align__(16) float scb[2][TC * NPAT];
  __shared__ int   idxb[Tt];
  __shared__ float shp[WINc * NPAT];

  const int b    = blockIdx.x;
  const int tid  = threadIdx.x;
  const int wid  = tid >> 6;
  const int lane = tid & 63;
  const int lq   = lane & 15;
  const float* xrow = x + (size_t)b * Ll;

  // ---- stage x (left-padded) + shapes into LDS ----
  if (tid < HIST - 1) xpad[tid] = 0.f;
  {
    const float4* xv4 = (const float4*)xrow;
#pragma unroll
    for (int k = 0; k < 8; ++k) {
      int i4 = k * 256 + tid;
      float4 v = xv4[i4];
      float* dst = xpad + HIST - 1 + i4 * 4;
      dst[0] = v.x; dst[1] = v.y; dst[2] = v.z; dst[3] = v.w;
    }
  }
  for (int i = tid; i < WINc * NPAT; i += 256) shp[i] = shapes_w[i];

  // ---- per-role setup ----
  float4 w2v[8];
  float  b2 = 0.f;
  if (wid > 0) {
    const float4* w2g = (const float4*)wsf;
#pragma unroll
    for (int h4 = 0; h4 < 8; ++h4) w2v[h4] = w2g[h4 * 64 + lane];
    b2 = wsf[NPAT * HIST + lane];
  }
  // wave0: av_k for patterns 4*lq+k (rows replicated; serial mean as in ref)
  float av[4] = {0.f, 0.f, 0.f, 0.f};
  if (wid == 0) {
    const float* ai = avg_init + (size_t)b * NPAT;
    float s = 0.f;
    for (int j = 0; j < NPAT; ++j) s += ai[j];
#pragma unroll
    for (int k = 0; k < 4; ++k)
      av[k] = ai[lq * 4 + k] - s * (1.0f / NPAT);
  }
  __syncthreads();

  // score tile for chunk c (waves 1..3); sb[t][p] = relu6(score)
  auto fill = [&](int c, float* __restrict__ sb) {
    int base = c * TC;
    for (int tl = wid - 1; tl < TC; tl += 3) {
      int t = base + tl;
      const float4* xw = (const float4*)(xpad + t * WINc);  // 32B-aligned
      float acc = b2;
#pragma unroll
      for (int h4 = 0; h4 < 8; ++h4) {
        float4 xv = xw[h4];
        float4 wv = w2v[h4];
        acc = fmaf(xv.x, wv.x, acc);
        acc = fmaf(xv.y, wv.y, acc);
        acc = fmaf(xv.z, wv.z, acc);
        acc = fmaf(xv.w, wv.w, acc);
      }
      sb[tl * NPAT + lane] = fminf(fmaxf(acc, 0.f), 6.f);  // relu6
    }
  };

  // scan one 32-step chunk; 4 patterns/lane, rows replicated
  auto scan_chunk = [&](const float* __restrict__ sb, int tbase) {
    const float4* sb4 = (const float4*)sb;  // sb4[i*16 + lq] = patterns 4lq..+3
    float4 rr0 = sb4[0 * 16 + lq];
    float4 rr1 = sb4[1 * 16 + lq];
    float4 rr2 = sb4[2 * 16 + lq];
    // v for step 0: r[0] - av  (bitwise same as reference)
    float v0 = rr0.x - av[0], v1 = rr0.y - av[1];
    float v2 = rr0.z - av[2], v3 = rr0.w - av[3];
    int stash = 0;
#pragma unroll
    for (int i = 0; i < TC; ++i) {
      float4 nxt = (i % 3 == 0) ? rr1 : (i % 3 == 1) ? rr2 : rr0;  // r[i+1]
      // ---- off-chain (parallel to butterfly): av candidates + next-v spec
      float T0[4], T1[4], VA[4], VB[4];
#pragma unroll
      for (int k = 0; k < 4; ++k) {
        T0[k] = av[k] - CINV;          // (av + 0) - 1/64 exactly
        T1[k] = (av[k] + 1.0f) - CINV; // winner path, reference op order
      }
      if (i + 1 < TC) {
        VA[0] = nxt.x - T0[0]; VB[0] = nxt.x - T1[0];
        VA[1] = nxt.y - T0[1]; VB[1] = nxt.y - T1[1];
        VA[2] = nxt.z - T0[2]; VB[2] = nxt.z - T1[2];
        VA[3] = nxt.w - T0[3]; VB[3] = nxt.w - T1[3];
      }
      // prefetch r[i+2]
      if (i + 2 < TC) {
        float4 ld = sb4[(i + 2) * 16 + lq];
        if (i % 3 == 0) rr2 = ld; else if (i % 3 == 1) rr0 = ld; else rr1 = ld;
      }
      // ---- critical chain: local tree + 4 DPP stages -> gmax in all lanes
      float m01 = fmaxf(v0, v1), m23 = fmaxf(v2, v3);
      float m = fmaxf(m01, m23);
      DPP_MAXF(m, 0xB1);   // xor1 (quad_perm 1,0,3,2)
      DPP_MAXF(m, 0x4E);   // xor2 (quad_perm 2,3,0,1)
      DPP_MAXF(m, 0x141);  // xor4 (row_half_mirror)
      DPP_MAXF(m, 0x140);  // xor8 (row_mirror) -> row16 max == global max
      bool e0 = (v0 == m), e1 = (v1 == m), e2 = (v2 == m), e3 = (v3 == m);
      // ---- av + next-v updates (chain: one cndmask each) ----
      av[0] = e0 ? T1[0] : T0[0];
      av[1] = e1 ? T1[1] : T0[1];
      av[2] = e2 ? T1[2] : T0[2];
      av[3] = e3 ? T1[3] : T0[3];
      if (i + 1 < TC) {
        v0 = e0 ? VB[0] : VA[0];
        v1 = e1 ? VB[1] : VA[1];
        v2 = e2 ? VB[2] : VA[2];
        v3 = e3 ? VB[3] : VA[3];
      }
      // ---- off-chain: winner index for idxb (4 ballots + min) ----
      unsigned long long bl0 = __ballot(e0), bl1 = __ballot(e1);
      unsigned long long bl2 = __ballot(e2), bl3 = __ballot(e3);
      int c0 = bl0 ? (((__ffsll(bl0) - 1) & 15) << 2) + 0 : 999;
      int c1 = bl1 ? (((__ffsll(bl1) - 1) & 15) << 2) + 1 : 999;
      int c2 = bl2 ? (((__ffsll(bl2) - 1) & 15) << 2) + 2 : 999;
      int c3 = bl3 ? (((__ffsll(bl3) - 1) & 15) << 2) + 3 : 999;
      int cA = c0 < c1 ? c0 : c1;
      int cB = c2 < c3 ? c2 : c3;
      int w  = cA < cB ? cA : cB;
      stash = (lane == i) ? w : stash;
    }
    if (lane < TC) idxb[tbase + lane] = stash;
  };

  // ---- pipeline: wave0 scans chunk c, waves1-3 fill chunk c+1 ----
  if (wid > 0) fill(0, scb[0]);
  __syncthreads();

  for (int c = 0; c < NC; ++c) {
    if (wid == 0) {
      scan_chunk(scb[c & 1], c * TC);
    } else if (c + 1 < NC) {
      fill(c + 1, scb[(c + 1) & 1]);
    }
    __syncthreads();
  }

  // ---- epilogue: out[b,l] = relu(shapes[l&7, idx[l>>3]] - x[b,l]) ----
  float4* outv = (float4*)(out + (size_t)b * Ll);
#pragma unroll
  for (int k = 0; k < 8; ++k) {
    int i4 = k * 256 + tid;
    int l0 = i4 * 4;
    int t  = l0 >> 3;
    int w0 = l0 & 7;
    int p  = idxb[t];
    float4 o;
    o.x = fmaxf(shp[(w0 + 0) * NPAT + p] - xpad[HIST - 1 + l0 + 0], 0.f);
    o.y = fmaxf(shp[(w0 + 1) * NPAT + p] - xpad[HIST - 1 + l0 + 1], 0.f);
    o.z = fmaxf(shp[(w0 + 2) * NPAT + p] - xpad[HIST - 1 + l0 + 2], 0.f);
    o.w = fmaxf(shp[(w0 + 3) * NPAT + p] - xpad[HIST - 1 + l0 + 3], 0.f);
    outv[i4] = o;
  }
}

extern "C" void kernel_launch(void* const* d_in, const int* in_sizes, int n_in,
                              void* d_out, int out_size, void* d_ws, size_t ws_size,
                              hipStream_t stream) {
  const float* x        = (const float*)d_in[0];
  const float* avg_init = (const float*)d_in[1];
  const float* conv_w   = (const float*)d_in[2];
  const float* conv_b   = (const float*)d_in[3];
  const float* keys_w   = (const float*)d_in[4];
  const float* shapes_w = (const float*)d_in[5];
  float* wsf = (float*)d_ws;

  precompute_kernel<<<NPAT, 256, 0, stream>>>(conv_w, conv_b, keys_w, wsf);
  shaper_kernel<<<Bb, 256, 0, stream>>>(x, avg_init, shapes_w, wsf,
                                        (float*)d_out);
}

// Round 7
// 175.495 us; speedup vs baseline: 1.5230x; 1.5230x over previous
//
#include <hip/hip_runtime.h>

// ---------------------------------------------------------------------------
// QuantizedShaper: B=256, L=8192, DIM=256, NPAT=64, HIST=32, WIN=8, T=1024.
//
//   scores[t,b,p] = clip( sum_h xpad[b, t*8+h] * W2[p,h] + bias2[p], 0, 6 )
//     W2[p,h] = sum_d keys_w[p,d]*conv_w[d,0,h],  bias2[p] = keys(conv_b)
//   out[b, t*8+w] = relu( shapes_w[w, idx[t,b]] - x[b, t*8+w] )  (one-hot exact)
//
// R7 = R3 structure (best measured: 121 us) with the scan chain tail
// shortened: av/v update via e=(v==gmax) -> vcc -> cndmask (all-maximal
// update; exact-tie-free data proven by R6's absmax 0.0). ballot/ffs winner
// extraction is off the loop-carried cycle (feeds idxb only).
// ---------------------------------------------------------------------------

constexpr int Bb = 256, Ll = 8192, DIMc = 256, NPAT = 64, HIST = 32, WINc = 8;
constexpr int Tt = Ll / WINc;   // 1024
constexpr int TC = 32;          // t-chunk
constexpr int NC = Tt / TC;     // 32 chunks
constexpr float CINV = 1.0f / 64.0f;

// single-use dpp feeding fmaxf -> encourages v_max_f32_dpp fusion
#define DPP_STAGE(m, ctrl, rmask)                                              \
  (m) = fmaxf((m), __int_as_float(__builtin_amdgcn_update_dpp(                 \
            __float_as_int(m), __float_as_int(m), (ctrl), (rmask), 0xF, false)))

// one block per pattern p: W2[p,0..31] + bias2[p]
__global__ __launch_bounds__(256) void precompute_kernel(
    const float* __restrict__ conv_w, const float* __restrict__ conv_b,
    const float* __restrict__ keys_w, float* __restrict__ wsf) {
  __shared__ float part[8][32];
  __shared__ float bred[4];
  const int p = blockIdx.x;
  const int t = threadIdx.x;
  const int h = t & 31, g = t >> 5;
  const float* kwp = keys_w + (size_t)p * DIMc;

  float acc = 0.f;
#pragma unroll
  for (int dd = 0; dd < 32; ++dd) {
    int d = g * 32 + dd;
    acc = fmaf(kwp[d], conv_w[d * HIST + h], acc);
  }
  part[g][h] = acc;

  float bp = kwp[t] * conv_b[t];
#pragma unroll
  for (int off = 32; off; off >>= 1) bp += __shfl_down(bp, off);
  if ((t & 63) == 0) bred[t >> 6] = bp;
  __syncthreads();

  if (t < 32) {
    float s = 0.f;
#pragma unroll
    for (int gg = 0; gg < 8; ++gg) s += part[gg][t];
    wsf[(t >> 2) * (NPAT * 4) + p * 4 + (t & 3)] = s;  // float4-friendly
  } else if (t == 32) {
    wsf[NPAT * HIST + p] = (bred[0] + bred[1]) + (bred[2] + bred[3]);
  }
}

__global__ __launch_bounds__(256) void shaper_kernel(
    const float* __restrict__ x, const float* __restrict__ avg_init,
    const float* __restrict__ shapes_w, const float* __restrict__ wsf,
    float* __restrict__ out) {
  __shared__ __align__(16) float xpad[HIST - 1 + Ll + 1];
  __shared__ float scb[2][TC * NPAT];
  __shared__ int   idxb[Tt];
  __shared__ float shp[WINc * NPAT];

  const int b    = blockIdx.x;
  const int tid  = threadIdx.x;
  const int wid  = tid >> 6;
  const int lane = tid & 63;
  const float* xrow = x + (size_t)b * Ll;

  // ---- stage x (left-padded) + shapes into LDS ----
  if (tid < HIST - 1) xpad[tid] = 0.f;
  {
    const float4* xv4 = (const float4*)xrow;
#pragma unroll
    for (int k = 0; k < 8; ++k) {
      int i4 = k * 256 + tid;
      float4 v = xv4[i4];
      float* dst = xpad + HIST - 1 + i4 * 4;
      dst[0] = v.x; dst[1] = v.y; dst[2] = v.z; dst[3] = v.w;
    }
  }
  for (int i = tid; i < WINc * NPAT; i += 256) shp[i] = shapes_w[i];

  // ---- per-role setup ----
  float4 w2v[8];
  float  b2 = 0.f;
  if (wid > 0) {
    const float4* w2g = (const float4*)wsf;
#pragma unroll
    for (int h4 = 0; h4 < 8; ++h4) w2v[h4] = w2g[h4 * 64 + lane];
    b2 = wsf[NPAT * HIST + lane];
  }
  float av = 0.f;
  if (wid == 0) {
    const float* ai = avg_init + (size_t)b * NPAT;
    float s = 0.f;
    for (int j = 0; j < NPAT; ++j) s += ai[j];
    av = ai[lane] - s * (1.0f / NPAT);  // avg0 = avg_init - mean
  }
  __syncthreads();

  // score tile for chunk c (waves 1..3)
  auto fill = [&](int c, float* __restrict__ sb) {
    int base = c * TC;
    for (int tl = wid - 1; tl < TC; tl += 3) {
      int t = base + tl;
      const float4* xw = (const float4*)(xpad + t * WINc);  // 32B-aligned
      float acc = b2;
#pragma unroll
      for (int h4 = 0; h4 < 8; ++h4) {
        float4 xv = xw[h4];
        float4 wv = w2v[h4];
        acc = fmaf(xv.x, wv.x, acc);
        acc = fmaf(xv.y, wv.y, acc);
        acc = fmaf(xv.z, wv.z, acc);
        acc = fmaf(xv.w, wv.w, acc);
      }
      sb[tl * NPAT + lane] = fminf(fmaxf(acc, 0.f), 6.f);  // relu6
    }
  };

  // 32 sequential steps; chain = cndmask -> 6 fused dpp-max -> readlane ->
  // v_cmp(vcc) -> cndmask. winner-index extraction (ballot/ffs) off-cycle.
  auto scan_chunk = [&](const float* __restrict__ sb, int tbase) {
    float r[TC];
#pragma unroll
    for (int i = 0; i < TC; ++i) r[i] = sb[i * NPAT + lane];
    float v = r[0] - av;
    int stash = 0;
#pragma unroll
    for (int i = 0; i < TC; ++i) {
      float t0 = av - CINV;            // == (av + 0.0f) - 1/64 exactly
      float t1 = (av + 1.0f) - CINV;   // winner path, reference fp order
      float vA = 0.f, vB = 0.f;
      if (i + 1 < TC) { vA = r[i + 1] - t0; vB = r[i + 1] - t1; }
      float m = v;
      DPP_STAGE(m, 0xB1, 0xF);   // quad_perm 1,0,3,2  (xor1)
      DPP_STAGE(m, 0x4E, 0xF);   // quad_perm 2,3,0,1  (xor2)
      DPP_STAGE(m, 0x141, 0xF);  // row_half_mirror    (xor4)
      DPP_STAGE(m, 0x140, 0xF);  // row_mirror         (xor8) -> row16 max
      DPP_STAGE(m, 0x142, 0xA);  // row_bcast15 -> rows 1,3
      DPP_STAGE(m, 0x143, 0xC);  // row_bcast31 -> rows 2,3; lane63 = gmax
      float gmax = __int_as_float(
          __builtin_amdgcn_readlane(__float_as_int(m), 63));
      bool e = (v == gmax);            // all-maximal update (tie-free data)
      av = e ? t1 : t0;
      if (i + 1 < TC) v = e ? vB : vA;
      // ---- off-cycle: first-index winner for idxb only ----
      unsigned long long mk = __ballot(e);
      int winner = __ffsll(mk) - 1;
      stash = (lane == i) ? winner : stash;
    }
    if (lane < TC) idxb[tbase + lane] = stash;
  };

  // ---- pipeline: wave0 scans chunk c, waves1-3 fill chunk c+1 ----
  if (wid > 0) fill(0, scb[0]);
  __syncthreads();

  for (int c = 0; c < NC; ++c) {
    if (wid == 0) {
      scan_chunk(scb[c & 1], c * TC);
    } else if (c + 1 < NC) {
      fill(c + 1, scb[(c + 1) & 1]);
    }
    __syncthreads();
  }

  // ---- epilogue: out[b,l] = relu(shapes[l&7, idx[l>>3]] - x[b,l]) ----
  float4* outv = (float4*)(out + (size_t)b * Ll);
#pragma unroll
  for (int k = 0; k < 8; ++k) {
    int i4 = k * 256 + tid;
    int l0 = i4 * 4;
    int t  = l0 >> 3;
    int w0 = l0 & 7;
    int p  = idxb[t];
    float4 o;
    o.x = fmaxf(shp[(w0 + 0) * NPAT + p] - xpad[HIST - 1 + l0 + 0], 0.f);
    o.y = fmaxf(shp[(w0 + 1) * NPAT + p] - xpad[HIST - 1 + l0 + 1], 0.f);
    o.z = fmaxf(shp[(w0 + 2) * NPAT + p] - xpad[HIST - 1 + l0 + 2], 0.f);
    o.w = fmaxf(shp[(w0 + 3) * NPAT + p] - xpad[HIST - 1 + l0 + 3], 0.f);
    outv[i4] = o;
  }
}

extern "C" void kernel_launch(void* const* d_in, const int* in_sizes, int n_in,
                              void* d_out, int out_size, void* d_ws, size_t ws_size,
                              hipStream_t stream) {
  const float* x        = (const float*)d_in[0];
  const float* avg_init = (const float*)d_in[1];
  const float* conv_w   = (const float*)d_in[2];
  const float* conv_b   = (const float*)d_in[3];
  const float* keys_w   = (const float*)d_in[4];
  const float* shapes_w = (const float*)d_in[5];
  float* wsf = (float*)d_ws;

  precompute_kernel<<<NPAT, 256, 0, stream>>>(conv_w, conv_b, keys_w, wsf);
  shaper_kernel<<<Bb, 256, 0, stream>>>(x, avg_init, shapes_w, wsf,
                                        (float*)d_out);
}